// Round 1
// baseline (3379.143 us; speedup 1.0000x reference)
//
#include <hip/hip_runtime.h>
#include <hip/hip_bf16.h>

#define NROWS 128           // B*E rows
#define NCOLS 4096          // N (already a power of 2; no padding)
#define KVAL  64
#define KP1   65            // k+1 ESP states
#define NEGV  (-1e30f)

// Static scratch: suffix and prefix ESP tables, [m][t][j], t in [0,4096], j in [0,64].
// 128 * 4097 * 65 floats = ~136 MB each. Fully rewritten every call (deterministic).
__device__ float g_suf[(size_t)NROWS * (NCOLS + 1) * KP1];
__device__ float g_pre[(size_t)NROWS * (NCOLS + 1) * KP1];

// Exact replica of jnp.logaddexp: max(a,b) + log1p(exp(-|a-b|))
__device__ __forceinline__ float lae(float a, float b) {
    float mx = fmaxf(a, b);
    float d  = fabsf(a - b);
    return mx + log1pf(expf(-d));
}

// theta[m][n] = scores[b=m>>1][n][e=m&1], scores layout (64, 4096, 2)
__device__ __forceinline__ float theta_at(const float* __restrict__ scores, int m, int n) {
    return scores[((size_t)(m >> 1) * NCOLS + (size_t)n) * 2 + (m & 1)];
}

// One wave per DP chain. blocks [0,128): suffix DP for row b (backward).
// blocks [128,256): prefix DP for row b-128 (forward).
// Lane l holds carry[l+1]; carry[0] is identically 0.0f.
__global__ __launch_bounds__(64) void dp_kernel(const float* __restrict__ scores) {
    int blk = blockIdx.x;
    int l = threadIdx.x;
    bool suffix = blk < NROWS;
    int m = suffix ? blk : (blk - NROWS);
    float* tab = suffix ? g_suf : g_pre;
    size_t rowbase = (size_t)m * (NCOLS + 1) * KP1;

    float s = NEGV;
    // initial state row: Tab[N] for suffix, P[0] for prefix
    {
        size_t t0 = suffix ? (size_t)NCOLS : 0;
        if (l == 0) tab[rowbase + t0 * KP1 + 0] = 0.0f;
        tab[rowbase + t0 * KP1 + (size_t)l + 1] = NEGV;
    }
    for (int step = 0; step < NCOLS; ++step) {
        int col = suffix ? (NCOLS - 1 - step) : step;
        float th = theta_at(scores, m, col);
        float prev = __shfl_up(s, 1);          // old carry[l] from lane l-1
        float b = ((l == 0) ? 0.0f : prev) + th;
        s = lae(s, b);                          // new carry[l+1]
        size_t tout = suffix ? (size_t)col : (size_t)(step + 1);
        if (l == 0) tab[rowbase + tout * KP1 + 0] = 0.0f;
        tab[rowbase + tout * KP1 + (size_t)l + 1] = s;
    }
}

// One wave per (ensemble, row) walker. Lane l evaluates p for hypothetical r=l+1,
// __ballot collects all inclusion bits; the wave-uniform state r selects its bit.
__global__ __launch_bounds__(64) void sample_kernel(const float* __restrict__ scores,
                                                    const float* __restrict__ u,
                                                    float* __restrict__ out) {
    int blk = blockIdx.x;            // 0..255
    int tens = blk >> 7;             // ensemble 0..1
    int m = blk & (NROWS - 1);       // row 0..127
    int l = threadIdx.x;
    size_t rowbase = (size_t)m * (NCOLS + 1) * KP1;
    const float* __restrict__ urow = u + ((size_t)tens * NROWS + m) * NCOLS;
    int b_ = m >> 1, e_ = m & 1;
    float* __restrict__ orow = out + (((size_t)tens * 64 + b_) * NCOLS) * 2 + e_;

    int r = KVAL;
    unsigned long long bits = 0ULL;
    for (int t = 0; t < NCOLS; ++t) {
        float th  = theta_at(scores, m, t);
        float num = g_suf[rowbase + (size_t)(t + 1) * KP1 + (size_t)l];       // Tab[t+1][r-1], r=l+1
        float den = g_suf[rowbase + (size_t)t * KP1 + (size_t)l + 1];         // Tab[t][r]
        float p   = expf((th + num) - den);                                   // (th + num) - den, like reference
        bool inc_l = urow[t] < p;
        unsigned long long mask = __ballot(inc_l);
        int inc = (r > 0) ? (int)((mask >> (r - 1)) & 1ULL) : 0;              // p==0 when r==0
        bits |= ((unsigned long long)inc) << (t & 63);
        r -= inc;
        if ((t & 63) == 63) {
            int n = (t & ~63) + l;   // flush 64 decisions, lane l writes column n
            orow[(size_t)n * 2] = (float)((bits >> l) & 1ULL);
            bits = 0ULL;
        }
    }
}

// marg[m][i] = exp(th_i + logsumexp_a(P[i][a] + S[i+1][63-a]) - P[N][64])
__global__ __launch_bounds__(256) void marg_kernel(const float* __restrict__ scores,
                                                   float* __restrict__ out) {
    int tid = blockIdx.x * blockDim.x + threadIdx.x;   // 0..524287
    int m = tid >> 12;
    int i = tid & (NCOLS - 1);
    size_t rowbase = (size_t)m * (NCOLS + 1) * KP1;
    const float* __restrict__ P = &g_pre[rowbase + (size_t)i * KP1];
    const float* __restrict__ S = &g_suf[rowbase + (size_t)(i + 1) * KP1];

    float M = -INFINITY, sum = 0.0f;
    #pragma unroll 8
    for (int a = 0; a < KVAL; ++a) {
        float v = P[a] + S[KVAL - 1 - a];
        if (v > M) { sum = sum * expf(M - v) + 1.0f; M = v; }
        else       { sum += expf(v - M); }
    }
    float lse = M + logf(sum);
    float den = g_pre[rowbase + (size_t)NCOLS * KP1 + KVAL];   // log E_k(all)
    float th  = theta_at(scores, m, i);
    float marg = expf(th + lse - den);

    size_t obase = (size_t)2 * 64 * NCOLS * 2;                 // after new_mask block
    out[obase + ((size_t)(m >> 1) * NCOLS + (size_t)i) * 2 + (m & 1)] = marg;
}

extern "C" void kernel_launch(void* const* d_in, const int* in_sizes, int n_in,
                              void* d_out, int out_size, void* d_ws, size_t ws_size,
                              hipStream_t stream) {
    const float* scores = (const float*)d_in[0];   // (64, 4096, 2)
    const float* u      = (const float*)d_in[1];   // (2, 128, 4096)
    float* out = (float*)d_out;

    dp_kernel<<<2 * NROWS, 64, 0, stream>>>(scores);                 // suffix + prefix tables
    sample_kernel<<<2 * NROWS, 64, 0, stream>>>(scores, u, out);     // new_mask
    marg_kernel<<<(NROWS * NCOLS) / 256, 256, 0, stream>>>(scores, out); // new_marginals
}

// Round 2
// 1697.803 us; speedup vs baseline: 1.9903x; 1.9903x over previous
//
#include <hip/hip_runtime.h>
#include <hip/hip_bf16.h>

#define NROWS 128           // B*E rows
#define NCOLS 4096          // N
#define KVAL  64
#define NEGV  (-1e30f)

// ESP tables, j=0 column (identically 0) NOT stored: slot j-1 holds state j.
// Layout: [m][t][64], t in [0,4096]. 128 * 4097 * 64 * 4B = 134 MB each.
__device__ float g_suf[(size_t)NROWS * (NCOLS + 1) * 64];
__device__ float g_pre[(size_t)NROWS * (NCOLS + 1) * 64];

// Exact replica of jnp.logaddexp: max(a,b) + log1p(exp(-|a-b|))
__device__ __forceinline__ float lae(float a, float b) {
    float mx = fmaxf(a, b);
    float d  = fabsf(a - b);
    return mx + log1pf(expf(-d));
}

// One wave per DP chain. blocks [0,128): suffix (backward). [128,256): prefix (forward).
// Lane l holds carry state j=l+1; state j=0 is identically 0.
__global__ __launch_bounds__(64) void dp_kernel(const float* __restrict__ scores) {
    int blk = blockIdx.x;
    int l = threadIdx.x;
    bool suf = (blk < NROWS);
    int m = suf ? blk : (blk - NROWS);
    float* __restrict__ tab = (suf ? g_suf : g_pre) + (size_t)m * (NCOLS + 1) * 64;
    const float* __restrict__ srow = scores + (size_t)(m >> 1) * (NCOLS * 2) + (m & 1);

    // init state row (cols 1..64 = NEG)
    tab[(suf ? (size_t)NCOLS : (size_t)0) * 64 + l] = NEGV;
    float s = NEGV;
    // θ tile prefetch: lane l holds θ for step t0+l (suffix walks columns backward)
    float th_tile = suf ? srow[(size_t)(NCOLS - 1 - l) * 2] : srow[(size_t)l * 2];
    for (int t0 = 0; t0 < NCOLS; t0 += 64) {
        int nb = t0 + 64;
        float th_next = 0.0f;
        if (nb < NCOLS)
            th_next = suf ? srow[(size_t)(NCOLS - 1 - nb - l) * 2]
                          : srow[(size_t)(nb + l) * 2];
        #pragma unroll 8
        for (int ss = 0; ss < 64; ++ss) {
            int step = t0 + ss;
            float th = __shfl(th_tile, ss);
            float prev = __shfl_up(s, 1);
            float b = ((l == 0) ? 0.0f : prev) + th;
            s = lae(s, b);
            size_t tout = suf ? (size_t)(NCOLS - 1 - step) : (size_t)(step + 1);
            tab[tout * 64 + l] = s;
        }
        th_tile = th_next;
    }
}

// ---- sampler: one wave per (ensemble, row) chain; lane l models r = l+1 ----
__device__ __forceinline__ void sample_body(int chain, int l,
                                            const float* __restrict__ scores,
                                            const float* __restrict__ u,
                                            float* __restrict__ out) {
    int tens = chain >> 7;           // ensemble
    int m = chain & (NROWS - 1);     // row
    const float* __restrict__ S = g_suf + (size_t)m * (NCOLS + 1) * 64;
    const float* __restrict__ urow = u + ((size_t)tens * NROWS + m) * NCOLS;
    const float* __restrict__ srow = scores + (size_t)(m >> 1) * (NCOLS * 2) + (m & 1);
    float* __restrict__ orow = out + (((size_t)tens * 64 + (m >> 1)) * NCOLS) * 2 + (m & 1);

    // D_t[l] = S[t][l+1] (slot l). den_t = D_t[l]; num_t = shfl_up(D_{t+1},1), lane0 -> 0.
    float Dcur = S[l];                       // row 0
    float N[16];
    #pragma unroll
    for (int j = 0; j < 16; ++j) N[j] = S[(size_t)(1 + j) * 64 + l];  // rows 1..16

    float u_tile  = urow[l];
    float th_tile = srow[(size_t)l * 2];

    int r = KVAL;
    unsigned long long bits = 0ULL;
    for (int t0 = 0; t0 < NCOLS; t0 += 64) {
        int nb = (t0 + 64 < NCOLS) ? (t0 + 64) : 0;   // clamp (values unused on last tile)
        float u_nxt  = urow[nb + l];
        float th_nxt = srow[(size_t)(nb + l) * 2];
        #pragma unroll
        for (int g = 0; g < 8; ++g) {
            int tb = t0 + g * 8;
            float P[8];
            #pragma unroll
            for (int j = 0; j < 8; ++j) {
                int rp = tb + 17 + j;
                if (rp > NCOLS) rp = NCOLS;          // harmless clamp at the tail
                P[j] = S[(size_t)rp * 64 + l];
            }
            #pragma unroll
            for (int ss = 0; ss < 8; ++ss) {
                int t = tb + ss;
                float Dnext = N[ss];
                float num = __shfl_up(Dnext, 1);
                if (l == 0) num = 0.0f;
                float den = Dcur;
                float th  = __shfl(th_tile, t & 63);
                float uu  = __shfl(u_tile,  t & 63);
                float p = expf((th + num) - den);     // same expression as reference
                unsigned long long mask = __ballot(uu < p);
                int inc = (r > 0) ? (int)((mask >> (r - 1)) & 1ULL) : 0;
                bits |= ((unsigned long long)inc) << (t & 63);
                r -= inc;
                Dcur = Dnext;
            }
            #pragma unroll
            for (int j = 0; j < 8; ++j) N[j] = N[j + 8];
            #pragma unroll
            for (int j = 0; j < 8; ++j) N[j + 8] = P[j];
        }
        int n = t0 + l;
        orow[(size_t)n * 2] = (float)((bits >> l) & 1ULL);
        bits = 0ULL;
        u_tile = u_nxt; th_tile = th_nxt;
    }
}

// ---- marginals: one wave per output element; lane l holds term a = l ----
__device__ __forceinline__ void marg_body(int w, int l,
                                          const float* __restrict__ scores,
                                          float* __restrict__ out) {
    int m = w >> 12;
    int i = w & (NCOLS - 1);
    size_t rowbase = (size_t)m * (NCOLS + 1) * 64;
    // v_a = P[i][a] + S[i+1][63-a], a = l
    float vP = (l == 0)  ? 0.0f : g_pre[rowbase + (size_t)i * 64 + (l - 1)];
    float vS = (l == 63) ? 0.0f : g_suf[rowbase + (size_t)(i + 1) * 64 + (62 - l)];
    float v = vP + vS;
    float M = v;
    #pragma unroll
    for (int off = 32; off; off >>= 1) M = fmaxf(M, __shfl_xor(M, off));
    float e = expf(v - M);
    float sum = e;
    #pragma unroll
    for (int off = 32; off; off >>= 1) sum += __shfl_xor(sum, off);
    if (l == 0) {
        float lse = M + logf(sum);
        float den = g_pre[rowbase + (size_t)NCOLS * 64 + 63];   // log E_k(full row)
        float th  = scores[((size_t)(m >> 1) * NCOLS + i) * 2 + (m & 1)];
        size_t obase = (size_t)2 * 64 * NCOLS * 2;
        out[obase + ((size_t)(m >> 1) * NCOLS + i) * 2 + (m & 1)] = expf(th + lse - den);
    }
}

#define SAMPLE_BLOCKS 64
#define MARG_BLOCKS   ((NROWS * NCOLS) / 4)    // 4 waves per 256-thread block

__global__ __launch_bounds__(256) void tail_kernel(const float* __restrict__ scores,
                                                   const float* __restrict__ u,
                                                   float* __restrict__ out) {
    int l = threadIdx.x & 63;
    int wib = threadIdx.x >> 6;
    if (blockIdx.x < SAMPLE_BLOCKS) {
        sample_body(blockIdx.x * 4 + wib, l, scores, u, out);
    } else {
        marg_body((blockIdx.x - SAMPLE_BLOCKS) * 4 + wib, l, scores, out);
    }
}

extern "C" void kernel_launch(void* const* d_in, const int* in_sizes, int n_in,
                              void* d_out, int out_size, void* d_ws, size_t ws_size,
                              hipStream_t stream) {
    const float* scores = (const float*)d_in[0];   // (64, 4096, 2) f32
    const float* u      = (const float*)d_in[1];   // (2, 128, 4096) f32
    float* out = (float*)d_out;

    dp_kernel<<<2 * NROWS, 64, 0, stream>>>(scores);
    tail_kernel<<<SAMPLE_BLOCKS + MARG_BLOCKS, 256, 0, stream>>>(scores, u, out);
}

// Round 3
// 642.872 us; speedup vs baseline: 5.2563x; 2.6410x over previous
//
#include <hip/hip_runtime.h>
#include <hip/hip_bf16.h>

#define NROWS 128           // B*E rows
#define NCOLS 4096          // N
#define KVAL  64
#define NEGV  (-1e30f)

// ESP tables, j=0 column (identically 0) NOT stored: slot j-1 holds state j.
// Layout: [m][t][64], t in [0,4096]. 128 * 4097 * 64 * 4B = 134 MB each.
__device__ float g_suf[(size_t)NROWS * (NCOLS + 1) * 64];
__device__ float g_pre[(size_t)NROWS * (NCOLS + 1) * 64];
__device__ float g_th [(size_t)NROWS * NCOLS];       // theta transposed: [m][t]

// wave-wide shift-up-by-1 via DPP wave_shr:1 (0x138); lane 0 -> 0.0f.
// VALU latency, replaces ds_bpermute-based __shfl_up in the carried chain.
__device__ __forceinline__ float wave_shr1_zero(float x) {
    int r = __builtin_amdgcn_update_dpp(0, __float_as_int(x), 0x138, 0xF, 0xF, true);
    return __int_as_float(r);
}

// fast logaddexp: max(a,b) + ln2 * log2(1 + exp2(-|a-b|*log2e))
// abs error ~1e-7 per step; replaces OCML expf+log1pf (~35 dependent instrs).
__device__ __forceinline__ float lae_fast(float a, float b) {
    float mx = fmaxf(a, b);
    float d  = fabsf(a - b);
    float e  = __builtin_amdgcn_exp2f(d * -1.4426950408889634f);
    float lg = __builtin_amdgcn_logf(1.0f + e);
    return fmaf(lg, 0.6931471805599453f, mx);
}

// scores (64,4096,2) -> g_th[m=2b+e][t]; gives uniform-address (scalar-load)
// theta reads in dp/sampler/marg.
__global__ void transpose_kernel(const float* __restrict__ scores) {
    int idx = blockIdx.x * blockDim.x + threadIdx.x;   // over 64*4096
    int b = idx >> 12, n = idx & (NCOLS - 1);
    float2 v = ((const float2*)scores)[idx];
    g_th[(size_t)(2 * b)     * NCOLS + n] = v.x;
    g_th[(size_t)(2 * b + 1) * NCOLS + n] = v.y;
}

// One wave per DP chain. blocks [0,128): suffix (backward). [128,256): prefix.
// Lane l holds carry state j=l+1; state j=0 is identically 0 (DPP zero-fill).
__global__ __launch_bounds__(64) void dp_kernel() {
    int blk = blockIdx.x;
    int l = threadIdx.x;
    bool suf = (blk < NROWS);
    int m = suf ? blk : (blk - NROWS);
    float* __restrict__ tab = (suf ? g_suf : g_pre) + (size_t)m * (NCOLS + 1) * 64;
    const float* __restrict__ th = g_th + (size_t)m * NCOLS;

    tab[(size_t)(suf ? NCOLS : 0) * 64 + l] = NEGV;    // init state row
    float s = NEGV;
    if (suf) {
        #pragma unroll 8
        for (int tt = 0; tt < NCOLS; ++tt) {
            int t = NCOLS - 1 - tt;
            float b = wave_shr1_zero(s) + th[t];       // th[t] uniform -> s_load
            s = lae_fast(s, b);
            tab[(size_t)t * 64 + l] = s;
        }
    } else {
        #pragma unroll 8
        for (int t = 0; t < NCOLS; ++t) {
            float b = wave_shr1_zero(s) + th[t];
            s = lae_fast(s, b);
            tab[(size_t)(t + 1) * 64 + l] = s;
        }
    }
}

// ---- sampler: one wave per (ensemble,row); lane l models r = l+1.
// Carried chain is only ballot -> bit-select -> r (SALU); everything else
// (table-row ring prefetch, scalar u/theta loads, expf) pipelines freely.
__device__ __forceinline__ void sample_body(int chain, int l,
                                            const float* __restrict__ u,
                                            float* __restrict__ out) {
    int tens = chain >> 7;
    int m = chain & (NROWS - 1);
    const float* __restrict__ S = g_suf + (size_t)m * (NCOLS + 1) * 64;
    const float* __restrict__ urow = u + ((size_t)tens * NROWS + m) * NCOLS;
    const float* __restrict__ trow = g_th + (size_t)m * NCOLS;
    float* __restrict__ orow = out + (((size_t)tens * 64 + (m >> 1)) * NCOLS) * 2 + (m & 1);

    float Dcur = S[l];                   // row t slot l = state l+1
    float N[16];
    #pragma unroll
    for (int j = 0; j < 16; ++j) N[j] = S[(size_t)(1 + j) * 64 + l];

    int r = KVAL;
    unsigned long long bits = 0ULL;
    for (int t0 = 0; t0 < NCOLS; t0 += 64) {
        #pragma unroll
        for (int g = 0; g < 8; ++g) {
            int tb = t0 + g * 8;
            float P[8];
            #pragma unroll
            for (int j = 0; j < 8; ++j) {
                int rp = tb + 17 + j;
                if (rp > NCOLS) rp = NCOLS;            // tail clamp (values unused)
                P[j] = S[(size_t)rp * 64 + l];
            }
            #pragma unroll
            for (int ss = 0; ss < 8; ++ss) {
                int t = tb + ss;
                float Dnext = N[ss];
                float num = wave_shr1_zero(Dnext);     // S[t+1][r-1], lane0 -> state0=0
                float den = Dcur;
                float p = expf((trow[t] + num) - den); // bit-identical to passing version
                unsigned long long mask = __ballot(urow[t] < p);
                int inc = (r > 0) ? (int)((mask >> (r - 1)) & 1ULL) : 0;
                bits |= ((unsigned long long)inc) << (t & 63);
                r -= inc;
                Dcur = Dnext;
            }
            #pragma unroll
            for (int j = 0; j < 8; ++j) N[j] = N[j + 8];
            #pragma unroll
            for (int j = 0; j < 8; ++j) N[j + 8] = P[j];
        }
        orow[(size_t)(t0 + l) * 2] = (float)((bits >> l) & 1ULL);
        bits = 0ULL;
    }
}

// ---- marginals: one wave per output element; lane l holds conv term a = l ----
__device__ __forceinline__ void marg_body(int w, int l, float* __restrict__ out) {
    int m = w >> 12;
    int i = w & (NCOLS - 1);
    size_t rowbase = (size_t)m * (NCOLS + 1) * 64;
    float vP = (l == 0)  ? 0.0f : g_pre[rowbase + (size_t)i * 64 + (l - 1)];
    float vS = (l == 63) ? 0.0f : g_suf[rowbase + (size_t)(i + 1) * 64 + (62 - l)];
    float v = vP + vS;
    float M = v;
    #pragma unroll
    for (int off = 32; off; off >>= 1) M = fmaxf(M, __shfl_xor(M, off));
    float e = expf(v - M);
    float sum = e;
    #pragma unroll
    for (int off = 32; off; off >>= 1) sum += __shfl_xor(sum, off);
    if (l == 0) {
        float lse = M + logf(sum);
        float den = g_pre[rowbase + (size_t)NCOLS * 64 + 63];   // log E_k(full row)
        float th  = g_th[(size_t)m * NCOLS + i];
        size_t obase = (size_t)2 * 64 * NCOLS * 2;
        out[obase + ((size_t)(m >> 1) * NCOLS + i) * 2 + (m & 1)] = expf(th + lse - den);
    }
}

#define SAMPLE_BLOCKS 64
#define MARG_BLOCKS   ((NROWS * NCOLS) / 4)    // 4 waves per 256-thread block

__global__ __launch_bounds__(256) void tail_kernel(const float* __restrict__ u,
                                                   float* __restrict__ out) {
    int l = threadIdx.x & 63;
    int wib = threadIdx.x >> 6;
    if (blockIdx.x < SAMPLE_BLOCKS) {
        sample_body(blockIdx.x * 4 + wib, l, u, out);
    } else {
        marg_body((blockIdx.x - SAMPLE_BLOCKS) * 4 + wib, l, out);
    }
}

extern "C" void kernel_launch(void* const* d_in, const int* in_sizes, int n_in,
                              void* d_out, int out_size, void* d_ws, size_t ws_size,
                              hipStream_t stream) {
    const float* scores = (const float*)d_in[0];   // (64, 4096, 2) f32
    const float* u      = (const float*)d_in[1];   // (2, 128, 4096) f32
    float* out = (float*)d_out;

    transpose_kernel<<<(64 * NCOLS) / 256, 256, 0, stream>>>(scores);
    dp_kernel<<<2 * NROWS, 64, 0, stream>>>();
    tail_kernel<<<SAMPLE_BLOCKS + MARG_BLOCKS, 256, 0, stream>>>(u, out);
}